// Round 5
// baseline (25139.143 us; speedup 1.0000x reference)
//
#include <hip/hip_runtime.h>
#include <cstdio>
#include <cstdint>

// V=30000, E=512, H=512, T=32, B=64, L=512
// eg layout: [t][e4:128][b:64][4]   (64 MB)  - float4 per (e4,b)
// h  layout: [t][c4:128][b:64][4]   (64 MB per dir)
// em layout: [t][b][tag]            (4 MB)
// wpack: [dir][wg:128][ks:8][sec:2][kc:16][r:16][j:4]  (16 MB)
//   sec 0 = W_ih (e-part), sec 1 = W_hh (h-part); k = ks*64 + kc*4 + j
//   r = gate*4 + col_local; global row = gate*512 + wg*4 + col_local
// sync: ctr[dir][step] (64B-strided ints). Producer: relaxed agent atomic_add
//   after sc1 h-stores drained (vmcnt(0)+barrier). Consumer: 1 poller/WG,
//   relaxed agent load until ==128; h then read with NORMAL cached loads
//   (safe: first touch of h[t] lines happens only after producer's
//   write-through store reached the coherence point; kernel-launch acquire
//   invalidates stale lines from previous graph replays).

// ---------------------------------------------------------------------------
// K0: embedding gather -> eg[t][e4][b][4]
// ---------------------------------------------------------------------------
__global__ __launch_bounds__(512) void k_gather(
    const int* __restrict__ x, const float* __restrict__ emb,
    float4* __restrict__ eg4)
{
    const int t   = blockIdx.x;
    const int tid = threadIdx.x;
    __shared__ int xv[64];
    if (tid < 64) xv[tid] = x[tid * 512 + t];
    __syncthreads();
    #pragma unroll
    for (int i = 0; i < 16; ++i) {
        const int flat = i * 512 + tid;       // 0..8191
        const int b  = flat & 63;
        const int e4 = flat >> 6;             // 0..127
        const float4 v = *reinterpret_cast<const float4*>(
            emb + (size_t)xv[b] * 512 + e4 * 4);
        eg4[((size_t)t * 128 + e4) * 64 + b] = v;
    }
}

// ---------------------------------------------------------------------------
// K0b: pack weights into per-wave contiguous blocks
// ---------------------------------------------------------------------------
__global__ __launch_bounds__(256) void k_pack(
    const float* __restrict__ wih_f, const float* __restrict__ whh_f,
    const float* __restrict__ wih_b, const float* __restrict__ whh_b,
    float* __restrict__ wpack)
{
    const int i = blockIdx.x * 256 + threadIdx.x;   // 0 .. 4194303
    const int j   = i & 3;
    const int r   = (i >> 2) & 15;
    const int kc  = (i >> 6) & 15;
    const int sec = (i >> 10) & 1;
    const int ks  = (i >> 11) & 7;
    const int wg  = (i >> 14) & 127;
    const int dir = (i >> 21) & 1;
    const int k   = ks * 64 + kc * 4 + j;           // 0..511
    const int g   = r >> 2, cl = r & 3;
    const int rg  = g * 512 + wg * 4 + cl;          // global gate row
    const float* wih = dir ? wih_b : wih_f;
    const float* whh = dir ? whh_b : whh_f;
    const float v = sec ? whh[(size_t)rg * 512 + k] : wih[(size_t)rg * 512 + k];
    wpack[i] = v;
}

// ---------------------------------------------------------------------------
// 64-element dot block: q = per-lane float4 stream (stride 64 float4s),
// w = wave-uniform packed weights [kc:16][r:16][j:4]
// ---------------------------------------------------------------------------
__device__ __forceinline__ void dot64(const float4* __restrict__ q,
                                      const float* __restrict__ w,
                                      float acc[16])
{
    float4 v[16];
    #pragma unroll
    for (int kc = 0; kc < 16; ++kc) v[kc] = q[(size_t)kc * 64];
    #pragma unroll
    for (int kc = 0; kc < 16; ++kc) {
        const float* wp = w + kc * 64;
        #pragma unroll
        for (int r = 0; r < 16; ++r) {
            acc[r] = fmaf(wp[r * 4 + 0], v[kc].x, acc[r]);
            acc[r] = fmaf(wp[r * 4 + 1], v[kc].y, acc[r]);
            acc[r] = fmaf(wp[r * 4 + 2], v[kc].z, acc[r]);
            acc[r] = fmaf(wp[r * 4 + 3], v[kc].w, acc[r]);
        }
    }
}

// ---------------------------------------------------------------------------
// K1: persistent BiLSTM recurrence. 256 WGs (128/dir) x 512 threads.
// WG owns 4 h-cols (16 gate rows). lane = b, wave = k-slice (split-k x8).
// e-part of step s+1 computed after h-store of step s (hides drain).
// ---------------------------------------------------------------------------
__global__ __launch_bounds__(512) void k_lstm(
    const float4* __restrict__ eg4, const float* __restrict__ wpack,
    const float* __restrict__ b_f, const float* __restrict__ b_b,
    float* __restrict__ h_f, float* __restrict__ h_b,
    int* __restrict__ bar)
{
    const int bid = blockIdx.x;
    const int dir = bid >> 7;
    const int wg  = bid & 127;
    float* HH        = dir ? h_b : h_f;
    const float4* HQ = reinterpret_cast<const float4*>(HH);
    const float* BS  = dir ? b_b : b_f;
    int* ctr = bar + (size_t)dir * 512 * 16;    // per-step slots, 64 B apart

    const int tid = threadIdx.x;
    const int b   = tid & 63;
    const int ks  = __builtin_amdgcn_readfirstlane(tid >> 6);

    __shared__ float part[8][16][64];   // 32 KB split-k exchange

    const float* wbase = wpack + (size_t)((dir * 128 + wg) * 8 + ks) * 2048;
    const float* wE = wbase;            // sec 0
    const float* wH = wbase + 1024;     // sec 1

    const int col = (tid >> 6) & 3;     // gate-phase column (tid<256)
    float bias4[4] = {0.f, 0.f, 0.f, 0.f};
    if (tid < 256) {
        #pragma unroll
        for (int g = 0; g < 4; ++g) bias4[g] = BS[g * 512 + wg * 4 + col];
    }
    float cst = 0.f;

    // prologue: e-part for step 0
    float eacc[16];
    #pragma unroll
    for (int r = 0; r < 16; ++r) eacc[r] = 0.f;
    {
        const int t0 = dir ? 511 : 0;
        dot64(eg4 + ((size_t)t0 * 128 + ks * 16) * 64 + b, wE, eacc);
    }

    for (int s = 0; s < 512; ++s) {
        const int t = dir ? (511 - s) : s;
        float acc[16];
        #pragma unroll
        for (int r = 0; r < 16; ++r) acc[r] = eacc[r];

        // ---- wait for step s-1, then h-part (normal cached float4 loads) ----
        if (s > 0) {
            if (tid == 0) {
                const int* fp = ctr + (size_t)(s - 1) * 16;
                while (__hip_atomic_load(fp, __ATOMIC_RELAXED,
                                         __HIP_MEMORY_SCOPE_AGENT) < 128)
                    __builtin_amdgcn_s_sleep(2);
            }
            __syncthreads();
            const int tp = dir ? (t + 1) : (t - 1);
            dot64(HQ + ((size_t)tp * 128 + ks * 16) * 64 + b, wH, acc);
        }

        // ---- split-k reduce ----
        #pragma unroll
        for (int r = 0; r < 16; ++r) part[ks][r][b] = acc[r];
        __syncthreads();

        // ---- gates + write-through h store ----
        if (tid < 256) {
            float g4[4];
            #pragma unroll
            for (int g = 0; g < 4; ++g) {
                const int r = g * 4 + col;
                float v = bias4[g];
                #pragma unroll
                for (int w = 0; w < 8; ++w) v += part[w][r][b];
                g4[g] = v;
            }
            const float si = 1.f / (1.f + expf(-g4[0]));
            const float sf = 1.f / (1.f + expf(-g4[1]));
            const float tg = tanhf(g4[2]);
            const float so = 1.f / (1.f + expf(-g4[3]));
            cst = sf * cst + si * tg;
            const float hvv = so * tanhf(cst);
            // h[t][c4=wg][b][j=col]: write-through agent store (no L2 alloc)
            __hip_atomic_store(&HH[(((size_t)t * 128 + wg) * 64 + b) * 4 + col],
                               hvv, __ATOMIC_RELAXED, __HIP_MEMORY_SCOPE_AGENT);
        }

        if (s < 511) {
            // ---- e-part for step s+1: overlaps the h-store drain ----
            const int tn = dir ? (t - 1) : (t + 1);
            #pragma unroll
            for (int r = 0; r < 16; ++r) eacc[r] = 0.f;
            dot64(eg4 + ((size_t)tn * 128 + ks * 16) * 64 + b, wE, eacc);

            asm volatile("s_waitcnt vmcnt(0)" ::: "memory");
            __syncthreads();
            if (tid == 0)
                __hip_atomic_fetch_add(ctr + (size_t)s * 16, 1,
                                       __ATOMIC_RELAXED,
                                       __HIP_MEMORY_SCOPE_AGENT);
        }
    }
}

// ---------------------------------------------------------------------------
// K2: emissions  em[t][b][tag] = [hf;hb](t,b,:) . W[tag][:] + bias
// h layout [t][c4][b][4]
// ---------------------------------------------------------------------------
__global__ __launch_bounds__(256) void k_em(
    const float* __restrict__ hf, const float* __restrict__ hb,
    const float* __restrict__ Wm, const float* __restrict__ bias,
    float* __restrict__ em)
{
    const int t   = blockIdx.x;
    const int tid = threadIdx.x;
    const int b   = tid & 63;
    const int tg  = tid >> 6;          // 0..3 -> tags [tg*8, tg*8+8)
    __shared__ float Wl[128][33];
    float acc[8] = {};

    for (int ch = 0; ch < 8; ++ch) {
        {
            const int tag = tid >> 3;   // 0..31
            const int kq  = tid & 7;    // 0..7
            const float* src = Wm + (size_t)tag * 1024 + ch * 128 + kq * 16;
            #pragma unroll
            for (int ii = 0; ii < 4; ++ii) {
                const float4 v = *reinterpret_cast<const float4*>(src + ii * 4);
                const int k0 = kq * 16 + ii * 4;
                Wl[k0 + 0][tag] = v.x; Wl[k0 + 1][tag] = v.y;
                Wl[k0 + 2][tag] = v.z; Wl[k0 + 3][tag] = v.w;
            }
        }
        __syncthreads();
        const float4* hsrc4 = (ch < 4)
            ? (reinterpret_cast<const float4*>(hf) + ((size_t)t * 128 + ch * 32) * 64 + b)
            : (reinterpret_cast<const float4*>(hb) + ((size_t)t * 128 + (ch - 4) * 32) * 64 + b);
        #pragma unroll 4
        for (int c4l = 0; c4l < 32; ++c4l) {
            const float4 h4 = hsrc4[(size_t)c4l * 64];
            const float ha[4] = {h4.x, h4.y, h4.z, h4.w};
            #pragma unroll
            for (int j = 0; j < 4; ++j)
                #pragma unroll
                for (int jt = 0; jt < 8; ++jt)
                    acc[jt] = fmaf(ha[j], Wl[c4l * 4 + j][tg * 8 + jt], acc[jt]);
        }
        __syncthreads();
    }

    #pragma unroll
    for (int jt = 0; jt < 8; ++jt) {
        const int tag = tg * 8 + jt;
        em[((size_t)t * 64 + b) * 32 + tag] = acc[jt] + bias[tag];
    }
}

// ---------------------------------------------------------------------------
// K3: Viterbi forward + backtrace, one wave per batch row.
// Matches reference order: (score + trans) + em, first-max argmax.
// ---------------------------------------------------------------------------
__global__ __launch_bounds__(64) void k_vit(
    const float* __restrict__ em, const float* __restrict__ startv,
    const float* __restrict__ endv, const float* __restrict__ trans,
    int* __restrict__ out)
{
    const int b    = blockIdx.x;
    const int lane = threadIdx.x;
    const int c    = lane & 31;
    const bool act = lane < 32;
    __shared__ unsigned char hist[511][32];
    __shared__ int outb[512];

    float tr[32];
    #pragma unroll 8
    for (int p = 0; p < 32; ++p) tr[p] = trans[p * 32 + c];

    float s = act ? (startv[c] + em[(size_t)b * 32 + c]) : -1e30f;

    for (int t = 1; t < 512; ++t) {
        const float emc = act ? em[((size_t)t * 64 + b) * 32 + c] : 0.f;
        float m = -1e30f; int arg = 0;
        #pragma unroll 8
        for (int p = 0; p < 32; ++p) {
            const float v = __shfl(s, p) + tr[p] + emc;   // (s+tr)+em, ref order
            if (v > m) { m = v; arg = p; }                // strict > => first max
        }
        if (act) { s = m; hist[t - 1][c] = (unsigned char)arg; }
    }

    s = act ? (s + endv[c]) : -1e30f;
    int idx = act ? c : 63;
    #pragma unroll
    for (int off = 32; off >= 1; off >>= 1) {
        const float om = __shfl_down(s, off);
        const int   oi = __shfl_down(idx, off);
        if (om > s || (om == s && oi < idx)) { s = om; idx = oi; }
    }
    idx = __shfl(idx, 0);

    if (lane == 0) {
        int tag = idx;
        outb[511] = tag;
        for (int t = 510; t >= 0; --t) { tag = hist[t][tag]; outb[t] = tag; }
    }
    __syncthreads();
    for (int i = lane; i < 512; i += 64) out[(size_t)b * 512 + i] = outb[i];
}

// ---------------------------------------------------------------------------
extern "C" void kernel_launch(void* const* d_in, const int* in_sizes, int n_in,
                              void* d_out, int out_size, void* d_ws, size_t ws_size,
                              hipStream_t stream)
{
    const int*   x      = (const int*)d_in[0];
    const float* emb    = (const float*)d_in[1];
    const float* w_ih_f = (const float*)d_in[2];
    const float* w_hh_f = (const float*)d_in[3];
    const float* b_f    = (const float*)d_in[4];
    const float* w_ih_b = (const float*)d_in[5];
    const float* w_hh_b = (const float*)d_in[6];
    const float* b_b    = (const float*)d_in[7];
    const float* Wm     = (const float*)d_in[8];
    const float* bvec   = (const float*)d_in[9];
    const float* startv = (const float*)d_in[10];
    const float* endv   = (const float*)d_in[11];
    const float* trans  = (const float*)d_in[12];
    int* out = (int*)d_out;

    float* ws    = (float*)d_ws;
    float* eg    = ws;                          // 16,777,216 f32 (64 MB)
    float* h_f   = ws + 16777216;               // 16,777,216 f32
    float* h_b   = ws + 33554432;               // 16,777,216 f32
    float* em    = ws + 50331648;               //  1,048,576 f32
    float* wpack = ws + 51380224;               //  4,194,304 f32 (16 MB)
    int*   bar   = (int*)(ws + 55574528);       //  16,384 ints (64 KB)

    const size_t need = (size_t)(55574528 + 16384) * 4;
    if (ws_size < need) {
        fprintf(stderr, "kernel_launch: ws too small: %zu < %zu\n", ws_size, need);
        return;
    }

    (void)hipMemsetAsync(bar, 0, 65536, stream);
    k_gather<<<dim3(512),   512, 0, stream>>>(x, emb, (float4*)eg);
    k_pack  <<<dim3(16384), 256, 0, stream>>>(w_ih_f, w_hh_f, w_ih_b, w_hh_b, wpack);
    k_lstm  <<<dim3(256),   512, 0, stream>>>((const float4*)eg, wpack, b_f, b_b,
                                              h_f, h_b, bar);
    k_em    <<<dim3(512),   256, 0, stream>>>(h_f, h_b, Wm, bvec, em);
    k_vit   <<<dim3(64),     64, 0, stream>>>(em, startv, endv, trans, out);
}

// Round 7
// 11065.636 us; speedup vs baseline: 2.2718x; 2.2718x over previous
//
#include <hip/hip_runtime.h>
#include <cstdio>
#include <cstdint>

// V=30000, E=512, H=512, T=32, B=64, L=512
// eg layout: [t][e4:128][b:64][4]   (64 MB)  - float4 per (e4,b)
// h  layout: [t][c4:128][b:64][4]   (64 MB per dir)
// em layout: [t][b][tag]            (4 MB)
// wpack: [dir][wg:128][ks:8][sec:2][kc:16][r:16][j:4]  (16 MB)
// sync (R4-proven protocol): per-WG flag slots flg[wg*16]; producer sets
//   flag=s+1 after its h stores (sc1 write-through) are drained
//   (vmcnt(0)+barrier). 128 parallel pollers per WG, relaxed agent loads.
// h data moves via device-scope (sc1) asm loads/stores: bypass stale per-XCD
//   L2, served at the coherence point, fully pipelined (unlike atomic loads).

typedef float f32x4 __attribute__((ext_vector_type(4)));

// ---------------------------------------------------------------------------
// K0: embedding gather -> eg[t][e4][b][4]
// ---------------------------------------------------------------------------
__global__ __launch_bounds__(512) void k_gather(
    const int* __restrict__ x, const float* __restrict__ emb,
    float4* __restrict__ eg4)
{
    const int t   = blockIdx.x;
    const int tid = threadIdx.x;
    __shared__ int xv[64];
    if (tid < 64) xv[tid] = x[tid * 512 + t];
    __syncthreads();
    #pragma unroll
    for (int i = 0; i < 16; ++i) {
        const int flat = i * 512 + tid;       // 0..8191
        const int b  = flat & 63;
        const int e4 = flat >> 6;             // 0..127
        const float4 v = *reinterpret_cast<const float4*>(
            emb + (size_t)xv[b] * 512 + e4 * 4);
        eg4[((size_t)t * 128 + e4) * 64 + b] = v;
    }
}

// ---------------------------------------------------------------------------
// K0b: pack weights into per-wave contiguous blocks
// ---------------------------------------------------------------------------
__global__ __launch_bounds__(256) void k_pack(
    const float* __restrict__ wih_f, const float* __restrict__ whh_f,
    const float* __restrict__ wih_b, const float* __restrict__ whh_b,
    float* __restrict__ wpack)
{
    const int i = blockIdx.x * 256 + threadIdx.x;   // 0 .. 4194303
    const int j   = i & 3;
    const int r   = (i >> 2) & 15;
    const int kc  = (i >> 6) & 15;
    const int sec = (i >> 10) & 1;
    const int ks  = (i >> 11) & 7;
    const int wg  = (i >> 14) & 127;
    const int dir = (i >> 21) & 1;
    const int k   = ks * 64 + kc * 4 + j;           // 0..511
    const int g   = r >> 2, cl = r & 3;
    const int rg  = g * 512 + wg * 4 + cl;          // global gate row
    const float* wih = dir ? wih_b : wih_f;
    const float* whh = dir ? whh_b : whh_f;
    const float v = sec ? whh[(size_t)rg * 512 + k] : wih[(size_t)rg * 512 + k];
    wpack[i] = v;
}

// ---------------------------------------------------------------------------
// e-part dot: q = per-lane float4 stream (cached loads), w = packed weights
// ---------------------------------------------------------------------------
__device__ __forceinline__ void dotE(const float4* __restrict__ q,
                                     const float* __restrict__ w,
                                     float acc[16])
{
    float4 v[16];
    #pragma unroll
    for (int kc = 0; kc < 16; ++kc) v[kc] = q[(size_t)kc * 64];
    #pragma unroll
    for (int kc = 0; kc < 16; ++kc) {
        const float* wp = w + kc * 64;
        #pragma unroll
        for (int r = 0; r < 16; ++r) {
            acc[r] = fmaf(wp[r * 4 + 0], v[kc].x, acc[r]);
            acc[r] = fmaf(wp[r * 4 + 1], v[kc].y, acc[r]);
            acc[r] = fmaf(wp[r * 4 + 2], v[kc].z, acc[r]);
            acc[r] = fmaf(wp[r * 4 + 3], v[kc].w, acc[r]);
        }
    }
}

// ---------------------------------------------------------------------------
// K1: persistent BiLSTM recurrence. 256 WGs (128/dir) x 512 threads.
// WG owns 4 h-cols (16 gate rows). lane = b, wave = k-slice (split-k x8).
// ---------------------------------------------------------------------------
__global__ __launch_bounds__(512) void k_lstm(
    const float4* __restrict__ eg4, const float* __restrict__ wpack,
    const float* __restrict__ b_f, const float* __restrict__ b_b,
    float* __restrict__ h_f, float* __restrict__ h_b,
    int* __restrict__ bar)
{
    const int bid = blockIdx.x;
    const int dir = bid >> 7;
    const int wg  = bid & 127;
    float* HH  = dir ? h_b : h_f;
    float4* HH4 = reinterpret_cast<float4*>(HH);
    const float4* HQ = reinterpret_cast<const float4*>(HH);
    const float* BS  = dir ? b_b : b_f;
    int* flg = bar + dir * 2048;        // 128 slots x 16 ints (64 B apart)

    const int tid = threadIdx.x;
    const int b   = tid & 63;
    const int ks  = __builtin_amdgcn_readfirstlane(tid >> 6);

    __shared__ float part[8][16][64];   // 32 KB split-k exchange
    __shared__ float hlds[64][5];       // padded h staging for coalesced store

    const float* wbase = wpack + (size_t)((dir * 128 + wg) * 8 + ks) * 2048;
    const float* wE = wbase;            // sec 0
    const float* wH = wbase + 1024;     // sec 1

    const int col = (tid >> 6) & 3;     // gate-phase column (tid<256)
    float bias4[4] = {0.f, 0.f, 0.f, 0.f};
    if (tid < 256) {
        #pragma unroll
        for (int g = 0; g < 4; ++g) bias4[g] = BS[g * 512 + wg * 4 + col];
    }
    float cst = 0.f;

    // prologue: e-part for step 0
    float eacc[16];
    #pragma unroll
    for (int r = 0; r < 16; ++r) eacc[r] = 0.f;
    {
        const int t0 = dir ? 511 : 0;
        dotE(eg4 + ((size_t)t0 * 128 + ks * 16) * 64 + b, wE, eacc);
    }

    for (int s = 0; s < 512; ++s) {
        const int t = dir ? (511 - s) : s;
        float acc[16];
        #pragma unroll
        for (int r = 0; r < 16; ++r) acc[r] = eacc[r];

        // ---- wait for step s-1, then h-part (pipelined sc1 dwordx4) ----
        if (s > 0) {
            if (tid < 128) {
                const int* fp = flg + tid * 16;
                while (__hip_atomic_load(fp, __ATOMIC_RELAXED,
                                         __HIP_MEMORY_SCOPE_AGENT) < s)
                    __builtin_amdgcn_s_sleep(1);
            }
            __syncthreads();

            const int tp = dir ? (t + 1) : (t - 1);
            const float4* hp = HQ + ((size_t)tp * 128 + ks * 16) * 64 + b;
            f32x4 hv[16];
            #pragma unroll
            for (int kc = 0; kc < 16; ++kc) {
                asm volatile("global_load_dwordx4 %0, %1, off sc1"
                             : "=v"(hv[kc]) : "v"(hp + (size_t)kc * 64));
            }
            asm volatile("s_waitcnt vmcnt(0)" ::: "memory");
            __builtin_amdgcn_sched_barrier(0);

            #pragma unroll
            for (int kc = 0; kc < 16; ++kc) {
                const float* wp = wH + kc * 64;
                #pragma unroll
                for (int r = 0; r < 16; ++r) {
                    acc[r] = fmaf(wp[r * 4 + 0], hv[kc][0], acc[r]);
                    acc[r] = fmaf(wp[r * 4 + 1], hv[kc][1], acc[r]);
                    acc[r] = fmaf(wp[r * 4 + 2], hv[kc][2], acc[r]);
                    acc[r] = fmaf(wp[r * 4 + 3], hv[kc][3], acc[r]);
                }
            }
        }

        // ---- split-k reduce ----
        #pragma unroll
        for (int r = 0; r < 16; ++r) part[ks][r][b] = acc[r];
        __syncthreads();

        // ---- gates -> hlds ----
        if (tid < 256) {
            float g4[4];
            #pragma unroll
            for (int g = 0; g < 4; ++g) {
                const int r = g * 4 + col;
                float v = bias4[g];
                #pragma unroll
                for (int w = 0; w < 8; ++w) v += part[w][r][b];
                g4[g] = v;
            }
            const float si = 1.f / (1.f + expf(-g4[0]));
            const float sf = 1.f / (1.f + expf(-g4[1]));
            const float tg = tanhf(g4[2]);
            const float so = 1.f / (1.f + expf(-g4[3]));
            cst = sf * cst + si * tg;
            hlds[b][col] = so * tanhf(cst);
        }
        __syncthreads();

        // ---- coalesced write-through h store (wave 0) + drain ----
        if (tid < 64) {
            f32x4 o;
            o[0] = hlds[tid][0]; o[1] = hlds[tid][1];
            o[2] = hlds[tid][2]; o[3] = hlds[tid][3];
            float4* dst = HH4 + ((size_t)t * 128 + wg) * 64 + tid;
            asm volatile("global_store_dwordx4 %0, %1, off sc1"
                         :: "v"(dst), "v"(o) : "memory");
            asm volatile("s_waitcnt vmcnt(0)" ::: "memory");
        }
        __syncthreads();

        if (s < 511) {
            if (tid == 0)
                __hip_atomic_store(flg + wg * 16, s + 1,
                                   __ATOMIC_RELAXED, __HIP_MEMORY_SCOPE_AGENT);
            // ---- e-part for step s+1 (off critical path) ----
            const int tn = dir ? (t - 1) : (t + 1);
            #pragma unroll
            for (int r = 0; r < 16; ++r) eacc[r] = 0.f;
            dotE(eg4 + ((size_t)tn * 128 + ks * 16) * 64 + b, wE, eacc);
        }
    }
}

// ---------------------------------------------------------------------------
// K2: emissions  em[t][b][tag] = [hf;hb](t,b,:) . W[tag][:] + bias
// h layout [t][c4][b][4]
// ---------------------------------------------------------------------------
__global__ __launch_bounds__(256) void k_em(
    const float* __restrict__ hf, const float* __restrict__ hb,
    const float* __restrict__ Wm, const float* __restrict__ bias,
    float* __restrict__ em)
{
    const int t   = blockIdx.x;
    const int tid = threadIdx.x;
    const int b   = tid & 63;
    const int tg  = tid >> 6;          // 0..3 -> tags [tg*8, tg*8+8)
    __shared__ float Wl[128][33];
    float acc[8] = {};

    for (int ch = 0; ch < 8; ++ch) {
        {
            const int tag = tid >> 3;   // 0..31
            const int kq  = tid & 7;    // 0..7
            const float* src = Wm + (size_t)tag * 1024 + ch * 128 + kq * 16;
            #pragma unroll
            for (int ii = 0; ii < 4; ++ii) {
                const float4 v = *reinterpret_cast<const float4*>(src + ii * 4);
                const int k0 = kq * 16 + ii * 4;
                Wl[k0 + 0][tag] = v.x; Wl[k0 + 1][tag] = v.y;
                Wl[k0 + 2][tag] = v.z; Wl[k0 + 3][tag] = v.w;
            }
        }
        __syncthreads();
        const float4* hsrc4 = (ch < 4)
            ? (reinterpret_cast<const float4*>(hf) + ((size_t)t * 128 + ch * 32) * 64 + b)
            : (reinterpret_cast<const float4*>(hb) + ((size_t)t * 128 + (ch - 4) * 32) * 64 + b);
        #pragma unroll 4
        for (int c4l = 0; c4l < 32; ++c4l) {
            const float4 h4 = hsrc4[(size_t)c4l * 64];
            const float ha[4] = {h4.x, h4.y, h4.z, h4.w};
            #pragma unroll
            for (int j = 0; j < 4; ++j)
                #pragma unroll
                for (int jt = 0; jt < 8; ++jt)
                    acc[jt] = fmaf(ha[j], Wl[c4l * 4 + j][tg * 8 + jt], acc[jt]);
        }
        __syncthreads();
    }

    #pragma unroll
    for (int jt = 0; jt < 8; ++jt) {
        const int tag = tg * 8 + jt;
        em[((size_t)t * 64 + b) * 32 + tag] = acc[jt] + bias[tag];
    }
}

// ---------------------------------------------------------------------------
// K3: Viterbi forward + backtrace, one wave per batch row.
// ---------------------------------------------------------------------------
__global__ __launch_bounds__(64) void k_vit(
    const float* __restrict__ em, const float* __restrict__ startv,
    const float* __restrict__ endv, const float* __restrict__ trans,
    int* __restrict__ out)
{
    const int b    = blockIdx.x;
    const int lane = threadIdx.x;
    const int c    = lane & 31;
    const bool act = lane < 32;
    __shared__ unsigned char hist[511][32];
    __shared__ int outb[512];

    float tr[32];
    #pragma unroll 8
    for (int p = 0; p < 32; ++p) tr[p] = trans[p * 32 + c];

    float s = act ? (startv[c] + em[(size_t)b * 32 + c]) : -1e30f;

    for (int t = 1; t < 512; ++t) {
        const float emc = act ? em[((size_t)t * 64 + b) * 32 + c] : 0.f;
        float m = -1e30f; int arg = 0;
        #pragma unroll 8
        for (int p = 0; p < 32; ++p) {
            const float v = __shfl(s, p) + tr[p] + emc;   // (s+tr)+em, ref order
            if (v > m) { m = v; arg = p; }                // strict > => first max
        }
        if (act) { s = m; hist[t - 1][c] = (unsigned char)arg; }
    }

    s = act ? (s + endv[c]) : -1e30f;
    int idx = act ? c : 63;
    #pragma unroll
    for (int off = 32; off >= 1; off >>= 1) {
        const float om = __shfl_down(s, off);
        const int   oi = __shfl_down(idx, off);
        if (om > s || (om == s && oi < idx)) { s = om; idx = oi; }
    }
    idx = __shfl(idx, 0);

    if (lane == 0) {
        int tag = idx;
        outb[511] = tag;
        for (int t = 510; t >= 0; --t) { tag = hist[t][tag]; outb[t] = tag; }
    }
    __syncthreads();
    for (int i = lane; i < 512; i += 64) out[(size_t)b * 512 + i] = outb[i];
}

// ---------------------------------------------------------------------------
extern "C" void kernel_launch(void* const* d_in, const int* in_sizes, int n_in,
                              void* d_out, int out_size, void* d_ws, size_t ws_size,
                              hipStream_t stream)
{
    const int*   x      = (const int*)d_in[0];
    const float* emb    = (const float*)d_in[1];
    const float* w_ih_f = (const float*)d_in[2];
    const float* w_hh_f = (const float*)d_in[3];
    const float* b_f    = (const float*)d_in[4];
    const float* w_ih_b = (const float*)d_in[5];
    const float* w_hh_b = (const float*)d_in[6];
    const float* b_b    = (const float*)d_in[7];
    const float* Wm     = (const float*)d_in[8];
    const float* bvec   = (const float*)d_in[9];
    const float* startv = (const float*)d_in[10];
    const float* endv   = (const float*)d_in[11];
    const float* trans  = (const float*)d_in[12];
    int* out = (int*)d_out;

    float* ws    = (float*)d_ws;
    float* eg    = ws;                          // 16,777,216 f32 (64 MB)
    float* h_f   = ws + 16777216;               // 16,777,216 f32
    float* h_b   = ws + 33554432;               // 16,777,216 f32
    float* em    = ws + 50331648;               //  1,048,576 f32
    float* wpack = ws + 51380224;               //  4,194,304 f32 (16 MB)
    int*   bar   = (int*)(ws + 55574528);       //  16,384 ints (64 KB)

    const size_t need = (size_t)(55574528 + 16384) * 4;
    if (ws_size < need) {
        fprintf(stderr, "kernel_launch: ws too small: %zu < %zu\n", ws_size, need);
        return;
    }

    (void)hipMemsetAsync(bar, 0, 65536, stream);
    k_gather<<<dim3(512),   512, 0, stream>>>(x, emb, (float4*)eg);
    k_pack  <<<dim3(16384), 256, 0, stream>>>(w_ih_f, w_hh_f, w_ih_b, w_hh_b, wpack);
    k_lstm  <<<dim3(256),   512, 0, stream>>>((const float4*)eg, wpack, b_f, b_b,
                                              h_f, h_b, bar);
    k_em    <<<dim3(512),   256, 0, stream>>>(h_f, h_b, Wm, bvec, em);
    k_vit   <<<dim3(64),     64, 0, stream>>>(em, startv, endv, trans, out);
}

// Round 8
// 8633.344 us; speedup vs baseline: 2.9119x; 1.2817x over previous
//
#include <hip/hip_runtime.h>
#include <cstdio>
#include <cstdint>

// V=30000, E=512, H=512, T=32, B=64, L=512
// eg layout: [t][e4:128][b:64][4]   (64 MB)  - float4 per (e4,b)
// h  layout: [t][c4:128][b:64][4]   (64 MB per dir)
// em layout: [t][b][tag]            (4 MB)
// wpack: [dir][wg:128][ks:8][sec:2][kc:16][r:16][j:4]  (16 MB)
// sync: ctr[dir][step] (64B-strided). Producer wave0: sc1 write-through h
//   stores -> vmcnt(0) -> lane0 relaxed agent fetch_add (fire-and-forget).
//   Consumer: ONE poller/WG, relaxed agent load until ==128.
// h consumer reads are NORMAL CACHED loads: safe because producers write
//   through (no XCD L2 holds pre-write lines), consumers first-touch after
//   the counter, and kernel dispatch invalidates per-XCD L2s (no stale
//   poison from before launch). 16 WGs/XCD share one L2 copy of h[t-1].

typedef float f32x4 __attribute__((ext_vector_type(4)));

// ---------------------------------------------------------------------------
// K0: embedding gather -> eg[t][e4][b][4]
// ---------------------------------------------------------------------------
__global__ __launch_bounds__(512) void k_gather(
    const int* __restrict__ x, const float* __restrict__ emb,
    float4* __restrict__ eg4)
{
    const int t   = blockIdx.x;
    const int tid = threadIdx.x;
    __shared__ int xv[64];
    if (tid < 64) xv[tid] = x[tid * 512 + t];
    __syncthreads();
    #pragma unroll
    for (int i = 0; i < 16; ++i) {
        const int flat = i * 512 + tid;       // 0..8191
        const int b  = flat & 63;
        const int e4 = flat >> 6;             // 0..127
        const float4 v = *reinterpret_cast<const float4*>(
            emb + (size_t)xv[b] * 512 + e4 * 4);
        eg4[((size_t)t * 128 + e4) * 64 + b] = v;
    }
}

// ---------------------------------------------------------------------------
// K0b: pack weights into per-wave contiguous blocks
// ---------------------------------------------------------------------------
__global__ __launch_bounds__(256) void k_pack(
    const float* __restrict__ wih_f, const float* __restrict__ whh_f,
    const float* __restrict__ wih_b, const float* __restrict__ whh_b,
    float* __restrict__ wpack)
{
    const int i = blockIdx.x * 256 + threadIdx.x;   // 0 .. 4194303
    const int j   = i & 3;
    const int r   = (i >> 2) & 15;
    const int kc  = (i >> 6) & 15;
    const int sec = (i >> 10) & 1;
    const int ks  = (i >> 11) & 7;
    const int wg  = (i >> 14) & 127;
    const int dir = (i >> 21) & 1;
    const int k   = ks * 64 + kc * 4 + j;           // 0..511
    const int g   = r >> 2, cl = r & 3;
    const int rg  = g * 512 + wg * 4 + cl;          // global gate row
    const float* wih = dir ? wih_b : wih_f;
    const float* whh = dir ? whh_b : whh_f;
    const float v = sec ? whh[(size_t)rg * 512 + k] : wih[(size_t)rg * 512 + k];
    wpack[i] = v;
}

// ---------------------------------------------------------------------------
// 64-k dot block: q = per-lane float4 stream (cached), w = packed weights
// ---------------------------------------------------------------------------
__device__ __forceinline__ void dot64(const float4* __restrict__ q,
                                      const float* __restrict__ w,
                                      float acc[16])
{
    float4 v[16];
    #pragma unroll
    for (int kc = 0; kc < 16; ++kc) v[kc] = q[(size_t)kc * 64];
    #pragma unroll
    for (int kc = 0; kc < 16; ++kc) {
        const float* wp = w + kc * 64;
        #pragma unroll
        for (int r = 0; r < 16; ++r) {
            acc[r] = fmaf(wp[r * 4 + 0], v[kc].x, acc[r]);
            acc[r] = fmaf(wp[r * 4 + 1], v[kc].y, acc[r]);
            acc[r] = fmaf(wp[r * 4 + 2], v[kc].z, acc[r]);
            acc[r] = fmaf(wp[r * 4 + 3], v[kc].w, acc[r]);
        }
    }
}

// ---------------------------------------------------------------------------
// K1: persistent BiLSTM recurrence. 256 WGs (128/dir) x 512 threads.
// WG owns 4 h-cols (16 gate rows). lane = b, wave = k-slice (split-k x8).
// ---------------------------------------------------------------------------
__global__ __launch_bounds__(512) void k_lstm(
    const float4* __restrict__ eg4, const float* __restrict__ wpack,
    const float* __restrict__ b_f, const float* __restrict__ b_b,
    float* __restrict__ h_f, float* __restrict__ h_b,
    int* __restrict__ bar)
{
    const int bid = blockIdx.x;
    const int dir = bid >> 7;
    const int wg  = bid & 127;
    float* HH  = dir ? h_b : h_f;
    float4* HH4 = reinterpret_cast<float4*>(HH);
    const float4* HQ = reinterpret_cast<const float4*>(HH);
    const float* BS  = dir ? b_b : b_f;
    int* ctr = bar + (size_t)dir * 512 * 16;    // per-step slots, 64 B apart

    const int tid = threadIdx.x;
    const int b   = tid & 63;
    const int ks  = __builtin_amdgcn_readfirstlane(tid >> 6);

    __shared__ float part[8][16][64];   // 32 KB split-k exchange
    __shared__ float hlds[64][5];       // padded h staging for coalesced store

    const float* wbase = wpack + (size_t)((dir * 128 + wg) * 8 + ks) * 2048;
    const float* wE = wbase;            // sec 0
    const float* wH = wbase + 1024;     // sec 1

    const int col = (tid >> 6) & 3;     // gate-phase column (tid<256)
    float bias4[4] = {0.f, 0.f, 0.f, 0.f};
    if (tid < 256) {
        #pragma unroll
        for (int g = 0; g < 4; ++g) bias4[g] = BS[g * 512 + wg * 4 + col];
    }
    float cst = 0.f;

    // prologue: e-part for step 0
    float eacc[16];
    #pragma unroll
    for (int r = 0; r < 16; ++r) eacc[r] = 0.f;
    {
        const int t0 = dir ? 511 : 0;
        dot64(eg4 + ((size_t)t0 * 128 + ks * 16) * 64 + b, wE, eacc);
    }

    for (int s = 0; s < 512; ++s) {
        const int t = dir ? (511 - s) : s;
        float acc[16];
        #pragma unroll
        for (int r = 0; r < 16; ++r) acc[r] = eacc[r];

        // ---- wait for step s-1 (single poller), then cached h-dot ----
        if (s > 0) {
            if (tid == 0) {
                const int* fp = ctr + (size_t)(s - 1) * 16;
                while (__hip_atomic_load(fp, __ATOMIC_RELAXED,
                                         __HIP_MEMORY_SCOPE_AGENT) < 128)
                    __builtin_amdgcn_s_sleep(1);
            }
            __syncthreads();
            const int tp = dir ? (t + 1) : (t - 1);
            dot64(HQ + ((size_t)tp * 128 + ks * 16) * 64 + b, wH, acc);
        }

        // ---- split-k reduce ----
        #pragma unroll
        for (int r = 0; r < 16; ++r) part[ks][r][b] = acc[r];
        __syncthreads();

        // ---- gates -> hlds ----
        if (tid < 256) {
            float g4[4];
            #pragma unroll
            for (int g = 0; g < 4; ++g) {
                const int r = g * 4 + col;
                float v = bias4[g];
                #pragma unroll
                for (int w = 0; w < 8; ++w) v += part[w][r][b];
                g4[g] = v;
            }
            const float si = 1.f / (1.f + expf(-g4[0]));
            const float sf = 1.f / (1.f + expf(-g4[1]));
            const float tg = tanhf(g4[2]);
            const float so = 1.f / (1.f + expf(-g4[3]));
            cst = sf * cst + si * tg;
            hlds[b][col] = so * tanhf(cst);
        }
        __syncthreads();

        // ---- wave0: coalesced sc1 store, drain, fire-and-forget publish ----
        if (tid < 64) {
            f32x4 o;
            o[0] = hlds[tid][0]; o[1] = hlds[tid][1];
            o[2] = hlds[tid][2]; o[3] = hlds[tid][3];
            float4* dst = HH4 + ((size_t)t * 128 + wg) * 64 + tid;
            asm volatile("global_store_dwordx4 %0, %1, off sc1"
                         :: "v"(dst), "v"(o) : "memory");
            asm volatile("s_waitcnt vmcnt(0)" ::: "memory");
            if (tid == 0 && s < 511)
                __hip_atomic_fetch_add(ctr + (size_t)s * 16, 1,
                                       __ATOMIC_RELAXED,
                                       __HIP_MEMORY_SCOPE_AGENT);
        }

        // ---- e-part for step s+1 (fills the wait window) ----
        if (s < 511) {
            const int tn = dir ? (t - 1) : (t + 1);
            #pragma unroll
            for (int r = 0; r < 16; ++r) eacc[r] = 0.f;
            dot64(eg4 + ((size_t)tn * 128 + ks * 16) * 64 + b, wE, eacc);
        }
    }
}

// ---------------------------------------------------------------------------
// K2: emissions  em[t][b][tag] = [hf;hb](t,b,:) . W[tag][:] + bias
// h layout [t][c4][b][4]
// ---------------------------------------------------------------------------
__global__ __launch_bounds__(256) void k_em(
    const float* __restrict__ hf, const float* __restrict__ hb,
    const float* __restrict__ Wm, const float* __restrict__ bias,
    float* __restrict__ em)
{
    const int t   = blockIdx.x;
    const int tid = threadIdx.x;
    const int b   = tid & 63;
    const int tg  = tid >> 6;          // 0..3 -> tags [tg*8, tg*8+8)
    __shared__ float Wl[128][33];
    float acc[8] = {};

    for (int ch = 0; ch < 8; ++ch) {
        {
            const int tag = tid >> 3;   // 0..31
            const int kq  = tid & 7;    // 0..7
            const float* src = Wm + (size_t)tag * 1024 + ch * 128 + kq * 16;
            #pragma unroll
            for (int ii = 0; ii < 4; ++ii) {
                const float4 v = *reinterpret_cast<const float4*>(src + ii * 4);
                const int k0 = kq * 16 + ii * 4;
                Wl[k0 + 0][tag] = v.x; Wl[k0 + 1][tag] = v.y;
                Wl[k0 + 2][tag] = v.z; Wl[k0 + 3][tag] = v.w;
            }
        }
        __syncthreads();
        const float4* hsrc4 = (ch < 4)
            ? (reinterpret_cast<const float4*>(hf) + ((size_t)t * 128 + ch * 32) * 64 + b)
            : (reinterpret_cast<const float4*>(hb) + ((size_t)t * 128 + (ch - 4) * 32) * 64 + b);
        #pragma unroll 4
        for (int c4l = 0; c4l < 32; ++c4l) {
            const float4 h4 = hsrc4[(size_t)c4l * 64];
            const float ha[4] = {h4.x, h4.y, h4.z, h4.w};
            #pragma unroll
            for (int j = 0; j < 4; ++j)
                #pragma unroll
                for (int jt = 0; jt < 8; ++jt)
                    acc[jt] = fmaf(ha[j], Wl[c4l * 4 + j][tg * 8 + jt], acc[jt]);
        }
        __syncthreads();
    }

    #pragma unroll
    for (int jt = 0; jt < 8; ++jt) {
        const int tag = tg * 8 + jt;
        em[((size_t)t * 64 + b) * 32 + tag] = acc[jt] + bias[tag];
    }
}

// ---------------------------------------------------------------------------
// K3: Viterbi forward + backtrace, one wave per batch row.
// ---------------------------------------------------------------------------
__global__ __launch_bounds__(64) void k_vit(
    const float* __restrict__ em, const float* __restrict__ startv,
    const float* __restrict__ endv, const float* __restrict__ trans,
    int* __restrict__ out)
{
    const int b    = blockIdx.x;
    const int lane = threadIdx.x;
    const int c    = lane & 31;
    const bool act = lane < 32;
    __shared__ unsigned char hist[511][32];
    __shared__ int outb[512];

    float tr[32];
    #pragma unroll 8
    for (int p = 0; p < 32; ++p) tr[p] = trans[p * 32 + c];

    float s = act ? (startv[c] + em[(size_t)b * 32 + c]) : -1e30f;

    for (int t = 1; t < 512; ++t) {
        const float emc = act ? em[((size_t)t * 64 + b) * 32 + c] : 0.f;
        float m = -1e30f; int arg = 0;
        #pragma unroll 8
        for (int p = 0; p < 32; ++p) {
            const float v = __shfl(s, p) + tr[p] + emc;   // (s+tr)+em, ref order
            if (v > m) { m = v; arg = p; }                // strict > => first max
        }
        if (act) { s = m; hist[t - 1][c] = (unsigned char)arg; }
    }

    s = act ? (s + endv[c]) : -1e30f;
    int idx = act ? c : 63;
    #pragma unroll
    for (int off = 32; off >= 1; off >>= 1) {
        const float om = __shfl_down(s, off);
        const int   oi = __shfl_down(idx, off);
        if (om > s || (om == s && oi < idx)) { s = om; idx = oi; }
    }
    idx = __shfl(idx, 0);

    if (lane == 0) {
        int tag = idx;
        outb[511] = tag;
        for (int t = 510; t >= 0; --t) { tag = hist[t][tag]; outb[t] = tag; }
    }
    __syncthreads();
    for (int i = lane; i < 512; i += 64) out[(size_t)b * 512 + i] = outb[i];
}

// ---------------------------------------------------------------------------
extern "C" void kernel_launch(void* const* d_in, const int* in_sizes, int n_in,
                              void* d_out, int out_size, void* d_ws, size_t ws_size,
                              hipStream_t stream)
{
    const int*   x      = (const int*)d_in[0];
    const float* emb    = (const float*)d_in[1];
    const float* w_ih_f = (const float*)d_in[2];
    const float* w_hh_f = (const float*)d_in[3];
    const float* b_f    = (const float*)d_in[4];
    const float* w_ih_b = (const float*)d_in[5];
    const float* w_hh_b = (const float*)d_in[6];
    const float* b_b    = (const float*)d_in[7];
    const float* Wm     = (const float*)d_in[8];
    const float* bvec   = (const float*)d_in[9];
    const float* startv = (const float*)d_in[10];
    const float* endv   = (const float*)d_in[11];
    const float* trans  = (const float*)d_in[12];
    int* out = (int*)d_out;

    float* ws    = (float*)d_ws;
    float* eg    = ws;                          // 16,777,216 f32 (64 MB)
    float* h_f   = ws + 16777216;               // 16,777,216 f32
    float* h_b   = ws + 33554432;               // 16,777,216 f32
    float* em    = ws + 50331648;               //  1,048,576 f32
    float* wpack = ws + 51380224;               //  4,194,304 f32 (16 MB)
    int*   bar   = (int*)(ws + 55574528);       //  16,384 ints (64 KB)

    const size_t need = (size_t)(55574528 + 16384) * 4;
    if (ws_size < need) {
        fprintf(stderr, "kernel_launch: ws too small: %zu < %zu\n", ws_size, need);
        return;
    }

    (void)hipMemsetAsync(bar, 0, 65536, stream);
    k_gather<<<dim3(512),   512, 0, stream>>>(x, emb, (float4*)eg);
    k_pack  <<<dim3(16384), 256, 0, stream>>>(w_ih_f, w_hh_f, w_ih_b, w_hh_b, wpack);
    k_lstm  <<<dim3(256),   512, 0, stream>>>((const float4*)eg, wpack, b_f, b_b,
                                              h_f, h_b, bar);
    k_em    <<<dim3(512),   256, 0, stream>>>(h_f, h_b, Wm, bvec, em);
    k_vit   <<<dim3(64),     64, 0, stream>>>(em, startv, endv, trans, out);
}